// Round 18
// baseline (47.866 us; speedup 1.0000x reference)
//
#include <hip/hip_runtime.h>
#include <stdint.h>

typedef unsigned long long u64;
typedef unsigned int u32;

#define BATCH 32
#define H 512
#define W 512
#define WPR 8                     // u64 words per row
#define WORDS_IMG (H * WPR)       // 4096
#define NPIX (H * W)

#define NSTRIP 8
#define OWN 64
#define NBLK (BATCH * NSTRIP)     // 256 (strip grid)

// strip geometry: 16 exact pairs, trapezoid-windowed (proven R11)
#define HALO1 32
#define RL1 128
#define PAIRS1 16
#define THR1 512

// tail geometry: 16 strips of 32 rows (2 blocks/CU)
#define NSTRIP_T 16
#define OWN_T 32
#define NBLK_T (BATCH * NSTRIP_T) // 512
#define ERL_T 36                  // OWN_T + 2+2 rows for double dilation

#define WP 9                      // padded LDS row stride (u64)

// ---------------- pack: y(int32 0/1) -> bitboards via 64-bit ballot ----------
// R10-proven: 2048 blocks (8/CU); each wave owns 16 words, loads hoisted.
__global__ __launch_bounds__(256) void pack_kernel(const int* __restrict__ y,
                                                   u64* __restrict__ words,
                                                   int* __restrict__ flags,
                                                   int* __restrict__ counter) {
    if (blockIdx.x == 0 && threadIdx.x == 0) { flags[0] = 0; counter[0] = 0; }
    int gtid = blockIdx.x * blockDim.x + threadIdx.x;
    int lane = gtid & 63;
    int wave = gtid >> 6;                       // 0..8191
    const int* yb = y + (size_t)wave * 16 * 64;
    u64* wb = words + (size_t)wave * 16;
    int v[16];
    #pragma unroll
    for (int i = 0; i < 16; ++i) v[i] = yb[i * 64 + lane];
    #pragma unroll
    for (int i = 0; i < 16; ++i) {
        u64 m = __ballot(v[i] != 0);
        if (lane == 0) wb[i] = m;
    }
}

// ---------------- bit-sliced Zhang-Suen sub-iteration helpers ----------------
__device__ __forceinline__ void fulladd(u64 a, u64 b, u64 c, u64& s, u64& cy) {
    u64 t = a ^ b;
    s = t ^ c;
    cy = (a & b) | (t & c);
}

// strip version: RLp rows, stride WP, 2 rows per thread
template<bool FIRST, int RLp>
__device__ __forceinline__ u64 subiter2(const u64* __restrict__ src,
                                        u64* __restrict__ dst,
                                        int rg, int wc) {
    const int r = 2 * rg;
    u64 C[4], L[4], R[4];
    #pragma unroll
    for (int i = 0; i < 4; ++i) {
        int rr = r - 1 + i;
        bool v = (rr >= 0) && (rr < RLp);
        const u64* row = src + rr * WP;
        C[i] = v ? row[wc] : 0ull;
        L[i] = (v && wc > 0) ? row[wc - 1] : 0ull;
        R[i] = (v && wc < 7) ? row[wc + 1] : 0ull;
    }
    u64 Wst[4], Est[4];
    #pragma unroll
    for (int i = 0; i < 4; ++i) {
        Wst[i] = (C[i] << 1) | (L[i] >> 63);
        Est[i] = (C[i] >> 1) | (R[i] << 63);
    }
    u64 diff = 0;
    #pragma unroll
    for (int k = 0; k < 2; ++k) {
        u64 P2 = C[k],     P9 = Wst[k],     P3 = Est[k];
        u64 cC = C[k + 1], P8 = Wst[k + 1], P4 = Est[k + 1];
        u64 P6 = C[k + 2], P7 = Wst[k + 2], P5 = Est[k + 2];

        u64 s1, c1, s2, c2, s3, c3, ts, tc, us, uc;
        fulladd(P2, P3, P4, s1, c1);
        fulladd(P5, P6, P7, s2, c2);
        s3 = P8 ^ P9; c3 = P8 & P9;
        fulladd(s1, s2, s3, ts, tc);
        fulladd(c1, c2, c3, us, uc);
        u64 vs = us ^ tc, vc = us & tc;
        u64 w4 = uc ^ vc, w8 = uc & vc;
        u64 condB = (vs | w4 | w8) & ~(w8 | (w4 & vs & ts));

        u64 seen, multi, t;
        t = ~P2 & P3; seen = t;  multi = 0;
        t = ~P3 & P4; multi |= seen & t; seen |= t;
        t = ~P4 & P5; multi |= seen & t; seen |= t;
        t = ~P5 & P6; multi |= seen & t; seen |= t;
        t = ~P6 & P7; multi |= seen & t; seen |= t;
        t = ~P7 & P8; multi |= seen & t; seen |= t;
        t = ~P8 & P9; multi |= seen & t; seen |= t;
        t = ~P9 & P2; multi |= seen & t; seen |= t;
        u64 ex1 = seen & ~multi;

        u64 cond = FIRST ? (~(P2 & P4 & P6) & ~(P4 & P6 & P8))
                         : (~(P2 & P4 & P8) & ~(P2 & P6 & P8));

        u64 rem = cC & condB & ex1 & cond;
        u64 nw = cC & ~rem;
        dst[(r + k) * WP + wc] = nw;
        diff |= nw ^ cC;
    }
    return diff;
}

// --------------- strip: 16 exact pairs, trapezoid-windowed (proven R11) -----
__global__ __launch_bounds__(THR1)
void strip16(const u64* __restrict__ gsrc, u64* __restrict__ gdst,
             int* __restrict__ flags) {
    __shared__ u64 A[RL1 * WP];
    __shared__ u64 Bf[RL1 * WP];
    __shared__ int s_any[2];

    const int tid = threadIdx.x;
    const int blk = blockIdx.x;
    const int b = blk >> 3;
    const int s = blk & 7;
    const int row0 = s * OWN;
    const int lane = tid & 63;
    const u64* src = gsrc + (size_t)b * WORDS_IMG;
    u64* dst = gdst + (size_t)b * WORDS_IMG;

    #pragma unroll
    for (int i = 0; i < 2; ++i) {
        int t = tid + i * THR1;
        int lrow = t >> 3, c = t & 7;
        int grow = row0 - HALO1 + lrow;
        u64 v = 0;
        if (grow >= 0 && grow < H) v = src[grow * WPR + c];
        A[lrow * WP + c] = v;
    }
    if (tid < 2) s_any[tid] = 0;
    __syncthreads();

    const int rg = tid >> 3;           // rows 2rg, 2rg+1
    const int wc = tid & 7;
    u64 lastown = 0;
    for (int pr = 0; pr < PAIRS1; ++pr) {
        // exactness window: only rows [2pr+1, 126-2pr] still matter
        const int lo = 2 * pr + 1;
        const int hi = 126 - 2 * pr;
        const bool active = (2 * rg + 1 >= lo) && (2 * rg <= hi);
        u64 d1 = 0, d2 = 0;
        if (active) d1 = subiter2<true, RL1>(A, Bf, rg, wc);
        __syncthreads();
        if (active) d2 = subiter2<false, RL1>(Bf, A, rg, wc);
        u64 d = d1 | d2;
        lastown = (rg >= 16 && rg < 48) ? d : 0;
        int p = pr & 1;
        u64 bal = __ballot(d != 0);
        if (lane == 0 && bal) atomicOr(&s_any[p], 1);
        __syncthreads();                  // A visible + s_any settled
        int any = s_any[p];
        if (tid == 0) s_any[p ^ 1] = 0;
        if (!any) break;                  // window fixpoint -> owned final
    }

    if (rg >= 16 && rg < 48) {
        int r = 2 * rg;
        dst[(row0 + r - HALO1) * WPR + wc]     = A[r * WP + wc];
        dst[(row0 + r - HALO1 + 1) * WPR + wc] = A[(r + 1) * WP + wc];
    }
    u64 bal = __ballot(lastown != 0);
    if (lane == 0 && bal) atomicOr(&flags[0], 1);
}

// full-image sub-iteration (stride WPR, 8 rows/thread) for the rare slow path
template<bool FIRST>
__device__ __forceinline__ void compute_sub_full(const u64* img, int wc, int r0,
                                                 u64 nw[8], u64& diff) {
    u64 C[10], L[10], R[10];
    #pragma unroll
    for (int i = 0; i < 10; ++i) {
        int rr = r0 - 1 + i;
        bool valid = (rr >= 0) && (rr < H);
        C[i] = valid ? img[rr * WPR + wc] : 0ull;
        L[i] = (valid && wc > 0) ? img[rr * WPR + wc - 1] : 0ull;
        R[i] = (valid && wc < WPR - 1) ? img[rr * WPR + wc + 1] : 0ull;
    }
    #pragma unroll
    for (int k = 0; k < 8; ++k) {
        u64 P2 = C[k];
        u64 P9 = (C[k]   << 1) | (L[k]   >> 63);
        u64 P3 = (C[k]   >> 1) | (R[k]   << 63);
        u64 cC = C[k+1];
        u64 P8 = (C[k+1] << 1) | (L[k+1] >> 63);
        u64 P4 = (C[k+1] >> 1) | (R[k+1] << 63);
        u64 P6 = C[k+2];
        u64 P7 = (C[k+2] << 1) | (L[k+2] >> 63);
        u64 P5 = (C[k+2] >> 1) | (R[k+2] << 63);

        u64 s1, c1, s2, c2, s3, c3, ts, tc, us, uc;
        fulladd(P2, P3, P4, s1, c1);
        fulladd(P5, P6, P7, s2, c2);
        s3 = P8 ^ P9; c3 = P8 & P9;
        fulladd(s1, s2, s3, ts, tc);
        fulladd(c1, c2, c3, us, uc);
        u64 vs = us ^ tc, vc = us & tc;
        u64 w4 = uc ^ vc, w8 = uc & vc;
        u64 condB = (vs | w4 | w8) & ~(w8 | (w4 & vs & ts));

        u64 seen, multi, t;
        t = ~P2 & P3; seen = t;  multi = 0;
        t = ~P3 & P4; multi |= seen & t; seen |= t;
        t = ~P4 & P5; multi |= seen & t; seen |= t;
        t = ~P5 & P6; multi |= seen & t; seen |= t;
        t = ~P6 & P7; multi |= seen & t; seen |= t;
        t = ~P7 & P8; multi |= seen & t; seen |= t;
        t = ~P8 & P9; multi |= seen & t; seen |= t;
        t = ~P9 & P2; multi |= seen & t; seen |= t;
        u64 ex1 = seen & ~multi;

        u64 cond = FIRST ? (~(P2 & P4 & P6) & ~(P4 & P6 & P8))
                         : (~(P2 & P4 & P8) & ~(P2 & P6 & P8));

        u64 rem = cC & condB & ex1 & cond;
        nw[k] = cC & ~rem;
        diff |= nw[k] ^ cC;
    }
}

// ---- tail: [gated in-LDS full fixpoint] + dilate x2 + gt + inter + final ---
// 512 blocks (2/CU), 32 owned rows each.
__global__ __launch_bounds__(512)
void tail_kernel(const u64* __restrict__ gB, const int* __restrict__ flags,
                 const float* __restrict__ x,
                 float* __restrict__ partial, int* __restrict__ partial_gt,
                 int* __restrict__ counter, float* __restrict__ out) {
    __shared__ u64 img[WORDS_IMG];     // 32 KB, used only on the rare path
    __shared__ u64 D[ERL_T * WP];
    __shared__ u64 E[ERL_T * WP];
    __shared__ float s_red[8];
    __shared__ int s_pc[8];
    __shared__ int s_last;
    __shared__ int s_changed;

    const int tid = threadIdx.x;
    const int blk = blockIdx.x;
    const int b = blk >> 4;
    const int s = blk & 15;
    const int row0 = s * OWN_T;
    const int lane = tid & 63;
    const int wv = tid >> 6;
    const u64* src = gB + (size_t)b * WORDS_IMG;

    // hoist all x loads (latency hides under the LDS work below)
    const float4* x4 = (const float4*)(x + (size_t)b * NPIX + (size_t)row0 * W);
    const int quad = tid & 127;        // float4 column 0..127
    const int rgp  = tid >> 7;         // 0..3
    float4 xv[8];
    #pragma unroll
    for (int i = 0; i < 8; ++i)
        xv[i] = x4[(i * 4 + rgp) * 128 + quad];

    const int ff = flags[0];           // uniform: strips exhausted 16 pairs?
    if (ff) {
        // redundant per-block full-image fixpoint in LDS (deterministic)
        const int wc2 = tid & 7;
        const int r02 = (tid >> 3) * 8;
        for (int t = tid; t < WORDS_IMG; t += 512) img[t] = src[t];
        if (tid == 0) s_changed = 0;
        __syncthreads();
        bool changed = true;
        for (int it = 0; it < 4096 && changed; ++it) {
            u64 diff = 0;
            u64 nw[8];
            compute_sub_full<true>(img, wc2, r02, nw, diff);
            __syncthreads();
            #pragma unroll
            for (int k = 0; k < 8; ++k) img[(r02 + k) * WPR + wc2] = nw[k];
            __syncthreads();
            compute_sub_full<false>(img, wc2, r02, nw, diff);
            __syncthreads();
            #pragma unroll
            for (int k = 0; k < 8; ++k) img[(r02 + k) * WPR + wc2] = nw[k];
            if (diff) atomicOr(&s_changed, 1);
            __syncthreads();
            changed = (s_changed != 0);
            __syncthreads();
            if (tid == 0) s_changed = 0;
        }
    }

    // load D rows row0-2 .. row0+33 from the converged mask
    if (tid < ERL_T * 8) {
        int lrow = tid >> 3, c = tid & 7;
        int grow = row0 - 2 + lrow;
        u64 v = 0;
        if (grow >= 0 && grow < H)
            v = ff ? img[grow * WPR + c] : src[grow * WPR + c];
        D[lrow * WP + c] = v;
    }
    __syncthreads();

    // dilate pass 1: D -> E (rows outside image forced to 0 = reference pad)
    if (tid < ERL_T * 8) {
        int l = tid >> 3, c = tid & 7;
        int grow = row0 - 2 + l;
        u64 v = 0;
        if (grow >= 0 && grow < H) {
            u64 cc = D[l * WP + c];
            u64 up = (l > 0)         ? D[(l - 1) * WP + c] : 0ull;
            u64 dn = (l < ERL_T - 1) ? D[(l + 1) * WP + c] : 0ull;
            u64 lw = (c > 0) ? D[l * WP + c - 1] : 0ull;
            u64 rw = (c < 7) ? D[l * WP + c + 1] : 0ull;
            v = cc | up | dn | ((cc << 1) | (lw >> 63)) | ((cc >> 1) | (rw << 63));
        }
        E[l * WP + c] = v;
    }
    __syncthreads();

    // dilate pass 2: owned rows only (LDS rows 2..33), one word per thread
    int pc = 0;
    u64 v = 0;
    if (tid < OWN_T * 8) {
        const int l = 2 + (tid >> 3);
        const int c = tid & 7;
        u64 cc = E[l * WP + c];
        u64 up = E[(l - 1) * WP + c];
        u64 dn = E[(l + 1) * WP + c];
        u64 lw = (c > 0) ? E[l * WP + c - 1] : 0ull;
        u64 rw = (c < 7) ? E[l * WP + c + 1] : 0ull;
        v = cc | up | dn | ((cc << 1) | (lw >> 63)) | ((cc >> 1) | (rw << 63));
        pc = __popcll(v);
    }
    for (int off = 32; off >= 1; off >>= 1) pc += __shfl_down(pc, off, 64);
    if (lane == 0) s_pc[wv] = pc;
    __syncthreads();          // E fully consumed by all threads
    if (tid < OWN_T * 8)
        D[(2 + (tid >> 3)) * WP + (tid & 7)] = v;   // dilated board into D
    __syncthreads();

    // intersection: registers (xv) x mask bits from D
    const int wi = quad >> 4;          // u64 word column
    const int sh = (quad & 15) * 4;    // bit offset within word
    float s0 = 0.0f, s1 = 0.0f, s2 = 0.0f, s3 = 0.0f;
    #pragma unroll
    for (int i = 0; i < 8; ++i) {
        int rrow = i * 4 + rgp;
        u64 word = D[(2 + rrow) * WP + wi];
        u32 bits = (u32)(word >> sh) & 0xFu;
        s0 = fmaf((float)(bits & 1u),        xv[i].x, s0);
        s1 = fmaf((float)((bits >> 1) & 1u), xv[i].y, s1);
        s2 = fmaf((float)((bits >> 2) & 1u), xv[i].z, s2);
        s3 = fmaf((float)((bits >> 3) & 1u), xv[i].w, s3);
    }
    float sum = (s0 + s1) + (s2 + s3);
    for (int off = 32; off >= 1; off >>= 1) sum += __shfl_down(sum, off, 64);
    if (lane == 0) s_red[wv] = sum;
    __syncthreads();

    if (tid == 0) {
        float fs = 0.0f;
        int is = 0;
        #pragma unroll
        for (int k = 0; k < 8; ++k) { fs += s_red[k]; is += s_pc[k]; }
        __hip_atomic_store(&partial[blk], fs, __ATOMIC_RELAXED,
                           __HIP_MEMORY_SCOPE_AGENT);
        __hip_atomic_store(&partial_gt[blk], is, __ATOMIC_RELAXED,
                           __HIP_MEMORY_SCOPE_AGENT);
        int prev = __hip_atomic_fetch_add(counter, 1, __ATOMIC_ACQ_REL,
                                          __HIP_MEMORY_SCOPE_AGENT);
        s_last = (prev == NBLK_T - 1);
    }
    __syncthreads();

    if (s_last && tid < 32) {
        float inter = 0.0f;
        int g = 0;
        #pragma unroll
        for (int j = 0; j < 16; ++j) {
            inter += __hip_atomic_load(&partial[tid * 16 + j], __ATOMIC_RELAXED,
                                       __HIP_MEMORY_SCOPE_AGENT);
            g += __hip_atomic_load(&partial_gt[tid * 16 + j], __ATOMIC_RELAXED,
                                   __HIP_MEMORY_SCOPE_AGENT);
        }
        float rec = (inter + 1.0f) / ((float)g + 1.0f);
        #pragma unroll
        for (int off = 16; off >= 1; off >>= 1)
            rec += __shfl_down(rec, off, 32);
        if (tid == 0) out[0] = -(rec / 32.0f);
    }
}

extern "C" void kernel_launch(void* const* d_in, const int* in_sizes, int n_in,
                              void* d_out, int out_size, void* d_ws, size_t ws_size,
                              hipStream_t stream) {
    const float* x = (const float*)d_in[0];
    const int*   y = (const int*)d_in[1];
    float* out = (float*)d_out;

    char* ws = (char*)d_ws;
    u64* gA = (u64*)ws;
    u64* gB = (u64*)(ws + (size_t)BATCH * WORDS_IMG * 8);
    int* flags = (int*)(ws + 2 * (size_t)BATCH * WORDS_IMG * 8);
    int* counter = flags + 4;
    float* partial = (float*)(counter + 4);
    int* partial_gt = (int*)(partial + NBLK_T);

    pack_kernel<<<2048, 256, 0, stream>>>(y, gA, flags, counter);
    strip16<<<NBLK, THR1, 0, stream>>>(gA, gB, flags);
    tail_kernel<<<NBLK_T, 512, 0, stream>>>(gB, flags, x, partial, partial_gt,
                                            counter, out);
}

// Round 19
// 43.201 us; speedup vs baseline: 1.1080x; 1.1080x over previous
//
#include <hip/hip_runtime.h>
#include <stdint.h>

typedef unsigned long long u64;
typedef unsigned int u32;

#define BATCH 32
#define H 512
#define W 512
#define WPR 8                     // u64 words per row
#define WORDS_IMG (H * WPR)       // 4096
#define NPIX (H * W)

#define NSTRIP 8
#define OWN 64
#define NBLK (BATCH * NSTRIP)     // 256

// strip geometry: 16 exact pairs, trapezoid-windowed (proven R11)
#define HALO1 32
#define RL1 128
#define PAIRS1 16
#define THR1 512

#define WP 9                      // padded LDS row stride (u64)
#define ERL 68                    // OWN + 2+2 rows for double dilation

// ---------------- pack: y(int32 0/1) -> bitboards via 64-bit ballot ----------
// R10-proven: 2048 blocks (8/CU); each wave owns 16 words, loads hoisted.
__global__ __launch_bounds__(256) void pack_kernel(const int* __restrict__ y,
                                                   u64* __restrict__ words,
                                                   int* __restrict__ flags,
                                                   int* __restrict__ counter) {
    if (blockIdx.x == 0 && threadIdx.x == 0) { flags[0] = 0; counter[0] = 0; }
    int gtid = blockIdx.x * blockDim.x + threadIdx.x;
    int lane = gtid & 63;
    int wave = gtid >> 6;                       // 0..8191
    const int* yb = y + (size_t)wave * 16 * 64;
    u64* wb = words + (size_t)wave * 16;
    int v[16];
    #pragma unroll
    for (int i = 0; i < 16; ++i) v[i] = yb[i * 64 + lane];
    #pragma unroll
    for (int i = 0; i < 16; ++i) {
        u64 m = __ballot(v[i] != 0);
        if (lane == 0) wb[i] = m;
    }
}

// ---------------- bit-sliced Zhang-Suen sub-iteration helpers ----------------
__device__ __forceinline__ void fulladd(u64 a, u64 b, u64 c, u64& s, u64& cy) {
    u64 t = a ^ b;
    s = t ^ c;
    cy = (a & b) | (t & c);
}

// strip version: RLp rows, stride WP, 2 rows per thread
template<bool FIRST, int RLp>
__device__ __forceinline__ u64 subiter2(const u64* __restrict__ src,
                                        u64* __restrict__ dst,
                                        int rg, int wc) {
    const int r = 2 * rg;
    u64 C[4], L[4], R[4];
    #pragma unroll
    for (int i = 0; i < 4; ++i) {
        int rr = r - 1 + i;
        bool v = (rr >= 0) && (rr < RLp);
        const u64* row = src + rr * WP;
        C[i] = v ? row[wc] : 0ull;
        L[i] = (v && wc > 0) ? row[wc - 1] : 0ull;
        R[i] = (v && wc < 7) ? row[wc + 1] : 0ull;
    }
    u64 Wst[4], Est[4];
    #pragma unroll
    for (int i = 0; i < 4; ++i) {
        Wst[i] = (C[i] << 1) | (L[i] >> 63);
        Est[i] = (C[i] >> 1) | (R[i] << 63);
    }
    u64 diff = 0;
    #pragma unroll
    for (int k = 0; k < 2; ++k) {
        u64 P2 = C[k],     P9 = Wst[k],     P3 = Est[k];
        u64 cC = C[k + 1], P8 = Wst[k + 1], P4 = Est[k + 1];
        u64 P6 = C[k + 2], P7 = Wst[k + 2], P5 = Est[k + 2];

        u64 s1, c1, s2, c2, s3, c3, ts, tc, us, uc;
        fulladd(P2, P3, P4, s1, c1);
        fulladd(P5, P6, P7, s2, c2);
        s3 = P8 ^ P9; c3 = P8 & P9;
        fulladd(s1, s2, s3, ts, tc);
        fulladd(c1, c2, c3, us, uc);
        u64 vs = us ^ tc, vc = us & tc;
        u64 w4 = uc ^ vc, w8 = uc & vc;
        u64 condB = (vs | w4 | w8) & ~(w8 | (w4 & vs & ts));

        u64 seen, multi, t;
        t = ~P2 & P3; seen = t;  multi = 0;
        t = ~P3 & P4; multi |= seen & t; seen |= t;
        t = ~P4 & P5; multi |= seen & t; seen |= t;
        t = ~P5 & P6; multi |= seen & t; seen |= t;
        t = ~P6 & P7; multi |= seen & t; seen |= t;
        t = ~P7 & P8; multi |= seen & t; seen |= t;
        t = ~P8 & P9; multi |= seen & t; seen |= t;
        t = ~P9 & P2; multi |= seen & t; seen |= t;
        u64 ex1 = seen & ~multi;

        u64 cond = FIRST ? (~(P2 & P4 & P6) & ~(P4 & P6 & P8))
                         : (~(P2 & P4 & P8) & ~(P2 & P6 & P8));

        u64 rem = cC & condB & ex1 & cond;
        u64 nw = cC & ~rem;
        dst[(r + k) * WP + wc] = nw;
        diff |= nw ^ cC;
    }
    return diff;
}

// --------------- strip: 16 exact pairs, trapezoid-windowed (proven R11) -----
__global__ __launch_bounds__(THR1)
void strip16(const u64* __restrict__ gsrc, u64* __restrict__ gdst,
             int* __restrict__ flags) {
    __shared__ u64 A[RL1 * WP];
    __shared__ u64 Bf[RL1 * WP];
    __shared__ int s_any[2];

    const int tid = threadIdx.x;
    const int blk = blockIdx.x;
    const int b = blk >> 3;
    const int s = blk & 7;
    const int row0 = s * OWN;
    const int lane = tid & 63;
    const u64* src = gsrc + (size_t)b * WORDS_IMG;
    u64* dst = gdst + (size_t)b * WORDS_IMG;

    #pragma unroll
    for (int i = 0; i < 2; ++i) {
        int t = tid + i * THR1;
        int lrow = t >> 3, c = t & 7;
        int grow = row0 - HALO1 + lrow;
        u64 v = 0;
        if (grow >= 0 && grow < H) v = src[grow * WPR + c];
        A[lrow * WP + c] = v;
    }
    if (tid < 2) s_any[tid] = 0;
    __syncthreads();

    const int rg = tid >> 3;           // rows 2rg, 2rg+1
    const int wc = tid & 7;
    u64 lastown = 0;
    for (int pr = 0; pr < PAIRS1; ++pr) {
        // exactness window: only rows [2pr+1, 126-2pr] still matter
        const int lo = 2 * pr + 1;
        const int hi = 126 - 2 * pr;
        const bool active = (2 * rg + 1 >= lo) && (2 * rg <= hi);
        u64 d1 = 0, d2 = 0;
        if (active) d1 = subiter2<true, RL1>(A, Bf, rg, wc);
        __syncthreads();
        if (active) d2 = subiter2<false, RL1>(Bf, A, rg, wc);
        u64 d = d1 | d2;
        lastown = (rg >= 16 && rg < 48) ? d : 0;
        int p = pr & 1;
        u64 bal = __ballot(d != 0);
        if (lane == 0 && bal) atomicOr(&s_any[p], 1);
        __syncthreads();                  // A visible + s_any settled
        int any = s_any[p];
        if (tid == 0) s_any[p ^ 1] = 0;
        if (!any) break;                  // window fixpoint -> owned final
    }

    if (rg >= 16 && rg < 48) {
        int r = 2 * rg;
        dst[(row0 + r - HALO1) * WPR + wc]     = A[r * WP + wc];
        dst[(row0 + r - HALO1 + 1) * WPR + wc] = A[(r + 1) * WP + wc];
    }
    u64 bal = __ballot(lastown != 0);
    if (lane == 0 && bal) atomicOr(&flags[0], 1);
}

// full-image sub-iteration (stride WPR, 8 rows/thread) for the rare slow path
template<bool FIRST>
__device__ __forceinline__ void compute_sub_full(const u64* img, int wc, int r0,
                                                 u64 nw[8], u64& diff) {
    u64 C[10], L[10], R[10];
    #pragma unroll
    for (int i = 0; i < 10; ++i) {
        int rr = r0 - 1 + i;
        bool valid = (rr >= 0) && (rr < H);
        C[i] = valid ? img[rr * WPR + wc] : 0ull;
        L[i] = (valid && wc > 0) ? img[rr * WPR + wc - 1] : 0ull;
        R[i] = (valid && wc < WPR - 1) ? img[rr * WPR + wc + 1] : 0ull;
    }
    #pragma unroll
    for (int k = 0; k < 8; ++k) {
        u64 P2 = C[k];
        u64 P9 = (C[k]   << 1) | (L[k]   >> 63);
        u64 P3 = (C[k]   >> 1) | (R[k]   << 63);
        u64 cC = C[k+1];
        u64 P8 = (C[k+1] << 1) | (L[k+1] >> 63);
        u64 P4 = (C[k+1] >> 1) | (R[k+1] << 63);
        u64 P6 = C[k+2];
        u64 P7 = (C[k+2] << 1) | (L[k+2] >> 63);
        u64 P5 = (C[k+2] >> 1) | (R[k+2] << 63);

        u64 s1, c1, s2, c2, s3, c3, ts, tc, us, uc;
        fulladd(P2, P3, P4, s1, c1);
        fulladd(P5, P6, P7, s2, c2);
        s3 = P8 ^ P9; c3 = P8 & P9;
        fulladd(s1, s2, s3, ts, tc);
        fulladd(c1, c2, c3, us, uc);
        u64 vs = us ^ tc, vc = us & tc;
        u64 w4 = uc ^ vc, w8 = uc & vc;
        u64 condB = (vs | w4 | w8) & ~(w8 | (w4 & vs & ts));

        u64 seen, multi, t;
        t = ~P2 & P3; seen = t;  multi = 0;
        t = ~P3 & P4; multi |= seen & t; seen |= t;
        t = ~P4 & P5; multi |= seen & t; seen |= t;
        t = ~P5 & P6; multi |= seen & t; seen |= t;
        t = ~P6 & P7; multi |= seen & t; seen |= t;
        t = ~P7 & P8; multi |= seen & t; seen |= t;
        t = ~P8 & P9; multi |= seen & t; seen |= t;
        t = ~P9 & P2; multi |= seen & t; seen |= t;
        u64 ex1 = seen & ~multi;

        u64 cond = FIRST ? (~(P2 & P4 & P6) & ~(P4 & P6 & P8))
                         : (~(P2 & P4 & P8) & ~(P2 & P6 & P8));

        u64 rem = cC & condB & ex1 & cond;
        nw[k] = cC & ~rem;
        diff |= nw[k] ^ cC;
    }
}

// ---- tail: [gated in-LDS full fixpoint] + dilate x2 + gt + inter + final ---
__global__ __launch_bounds__(512)
void tail_kernel(const u64* __restrict__ gB, const int* __restrict__ flags,
                 const float* __restrict__ x,
                 float* __restrict__ partial, int* __restrict__ partial_gt,
                 int* __restrict__ counter, float* __restrict__ out) {
    __shared__ u64 img[WORDS_IMG];     // 32 KB, used only on the rare path
    __shared__ u64 D[ERL * WP];
    __shared__ u64 E[ERL * WP];
    __shared__ float s_red[8];
    __shared__ int s_pc[8];
    __shared__ int s_last;
    __shared__ int s_changed;

    const int tid = threadIdx.x;
    const int blk = blockIdx.x;
    const int b = blk >> 3;
    const int s = blk & 7;
    const int row0 = s * OWN;
    const int lane = tid & 63;
    const int wv = tid >> 6;
    const u64* src = gB + (size_t)b * WORDS_IMG;

    // hoist all x loads (latency hides under the LDS work below)
    const float4* x4 = (const float4*)(x + (size_t)b * NPIX + (size_t)row0 * W);
    const int quad = tid & 127;        // float4 column 0..127
    const int rgp  = tid >> 7;         // 0..3
    float4 xv[16];
    #pragma unroll
    for (int i = 0; i < 16; ++i)
        xv[i] = x4[(i * 4 + rgp) * 128 + quad];

    const int ff = flags[0];           // uniform: strips exhausted 16 pairs?
    if (ff) {
        // redundant per-block full-image fixpoint in LDS (deterministic)
        const int wc2 = tid & 7;
        const int r02 = (tid >> 3) * 8;
        for (int t = tid; t < WORDS_IMG; t += 512) img[t] = src[t];
        if (tid == 0) s_changed = 0;
        __syncthreads();
        bool changed = true;
        for (int it = 0; it < 4096 && changed; ++it) {
            u64 diff = 0;
            u64 nw[8];
            compute_sub_full<true>(img, wc2, r02, nw, diff);
            __syncthreads();
            #pragma unroll
            for (int k = 0; k < 8; ++k) img[(r02 + k) * WPR + wc2] = nw[k];
            __syncthreads();
            compute_sub_full<false>(img, wc2, r02, nw, diff);
            __syncthreads();
            #pragma unroll
            for (int k = 0; k < 8; ++k) img[(r02 + k) * WPR + wc2] = nw[k];
            if (diff) atomicOr(&s_changed, 1);
            __syncthreads();
            changed = (s_changed != 0);
            __syncthreads();
            if (tid == 0) s_changed = 0;
        }
    }

    // load D rows row0-2 .. row0+65 from the converged mask
    for (int t = tid; t < ERL * 8; t += 512) {
        int lrow = t >> 3, c = t & 7;
        int grow = row0 - 2 + lrow;
        u64 v = 0;
        if (grow >= 0 && grow < H)
            v = ff ? img[grow * WPR + c] : src[grow * WPR + c];
        D[lrow * WP + c] = v;
    }
    __syncthreads();

    // dilate pass 1: D -> E (rows outside image forced to 0 = reference pad)
    for (int t = tid; t < ERL * 8; t += 512) {
        int l = t >> 3, c = t & 7;
        int grow = row0 - 2 + l;
        u64 v = 0;
        if (grow >= 0 && grow < H) {
            u64 cc = D[l * WP + c];
            u64 up = (l > 0)       ? D[(l - 1) * WP + c] : 0ull;
            u64 dn = (l < ERL - 1) ? D[(l + 1) * WP + c] : 0ull;
            u64 lw = (c > 0) ? D[l * WP + c - 1] : 0ull;
            u64 rw = (c < 7) ? D[l * WP + c + 1] : 0ull;
            v = cc | up | dn | ((cc << 1) | (lw >> 63)) | ((cc >> 1) | (rw << 63));
        }
        E[l * WP + c] = v;
    }
    __syncthreads();

    // dilate pass 2: owned rows only (LDS rows 2..65), one word per thread
    const int l = 2 + (tid >> 3);
    const int c = tid & 7;
    u64 v;
    {
        u64 cc = E[l * WP + c];
        u64 up = E[(l - 1) * WP + c];
        u64 dn = E[(l + 1) * WP + c];
        u64 lw = (c > 0) ? E[l * WP + c - 1] : 0ull;
        u64 rw = (c < 7) ? E[l * WP + c + 1] : 0ull;
        v = cc | up | dn | ((cc << 1) | (lw >> 63)) | ((cc >> 1) | (rw << 63));
    }
    int pc = __popcll(v);
    for (int off = 32; off >= 1; off >>= 1) pc += __shfl_down(pc, off, 64);
    if (lane == 0) s_pc[wv] = pc;
    __syncthreads();          // E fully consumed by all threads
    D[l * WP + c] = v;        // store dilated board into D
    __syncthreads();

    // intersection: registers (xv) x mask bits from D
    const int wi = quad >> 4;          // u64 word column
    const int sh = (quad & 15) * 4;    // bit offset within word
    float s0 = 0.0f, s1 = 0.0f, s2 = 0.0f, s3 = 0.0f;
    #pragma unroll
    for (int i = 0; i < 16; ++i) {
        int rrow = i * 4 + rgp;
        u64 word = D[(2 + rrow) * WP + wi];
        u32 bits = (u32)(word >> sh) & 0xFu;
        s0 = fmaf((float)(bits & 1u),        xv[i].x, s0);
        s1 = fmaf((float)((bits >> 1) & 1u), xv[i].y, s1);
        s2 = fmaf((float)((bits >> 2) & 1u), xv[i].z, s2);
        s3 = fmaf((float)((bits >> 3) & 1u), xv[i].w, s3);
    }
    float sum = (s0 + s1) + (s2 + s3);
    for (int off = 32; off >= 1; off >>= 1) sum += __shfl_down(sum, off, 64);
    if (lane == 0) s_red[wv] = sum;
    __syncthreads();

    if (tid == 0) {
        float fs = 0.0f;
        int is = 0;
        #pragma unroll
        for (int k = 0; k < 8; ++k) { fs += s_red[k]; is += s_pc[k]; }
        __hip_atomic_store(&partial[blk], fs, __ATOMIC_RELAXED,
                           __HIP_MEMORY_SCOPE_AGENT);
        __hip_atomic_store(&partial_gt[blk], is, __ATOMIC_RELAXED,
                           __HIP_MEMORY_SCOPE_AGENT);
        int prev = __hip_atomic_fetch_add(counter, 1, __ATOMIC_ACQ_REL,
                                          __HIP_MEMORY_SCOPE_AGENT);
        s_last = (prev == NBLK - 1);
    }
    __syncthreads();

    if (s_last && tid < 32) {
        float inter = 0.0f;
        int g = 0;
        #pragma unroll
        for (int j = 0; j < 8; ++j) {
            inter += __hip_atomic_load(&partial[tid * 8 + j], __ATOMIC_RELAXED,
                                       __HIP_MEMORY_SCOPE_AGENT);
            g += __hip_atomic_load(&partial_gt[tid * 8 + j], __ATOMIC_RELAXED,
                                   __HIP_MEMORY_SCOPE_AGENT);
        }
        float rec = (inter + 1.0f) / ((float)g + 1.0f);
        #pragma unroll
        for (int off = 16; off >= 1; off >>= 1)
            rec += __shfl_down(rec, off, 32);
        if (tid == 0) out[0] = -(rec / 32.0f);
    }
}

extern "C" void kernel_launch(void* const* d_in, const int* in_sizes, int n_in,
                              void* d_out, int out_size, void* d_ws, size_t ws_size,
                              hipStream_t stream) {
    const float* x = (const float*)d_in[0];
    const int*   y = (const int*)d_in[1];
    float* out = (float*)d_out;

    char* ws = (char*)d_ws;
    u64* gA = (u64*)ws;
    u64* gB = (u64*)(ws + (size_t)BATCH * WORDS_IMG * 8);
    int* flags = (int*)(ws + 2 * (size_t)BATCH * WORDS_IMG * 8);
    int* counter = flags + 4;
    float* partial = (float*)(counter + 4);
    int* partial_gt = (int*)(partial + NBLK);

    pack_kernel<<<2048, 256, 0, stream>>>(y, gA, flags, counter);
    strip16<<<NBLK, THR1, 0, stream>>>(gA, gB, flags);
    tail_kernel<<<NBLK, 512, 0, stream>>>(gB, flags, x, partial, partial_gt,
                                          counter, out);
}